// Round 8
// baseline (9160.328 us; speedup 1.0000x reference)
//
#include <hip/hip_runtime.h>
#include <hip/hip_fp16.h>

#define H 161
#define G4 644            // 4*H gates
#define BB 32             // batch
#define TT 1000           // time
#define M_TOT (BB*TT)     // 32000 rows
#define GP 164            // padded gate-plane stride (halves), 8B-aligned quads
#define PR4 (4*GP)        // 656 halves per (d,m) row of pre
#define KS2 200           // h buffer row: 192 used + pad, 400 B (16B-aligned)

typedef _Float16 f16x8 __attribute__((ext_vector_type(8)));
typedef float f32x4 __attribute__((ext_vector_type(4)));
typedef _Float16 h2_t __attribute__((ext_vector_type(2)));

__device__ __forceinline__ h2_t bc_h2(unsigned int u) {
    return __builtin_bit_cast(h2_t, u);
}

__device__ __forceinline__ float sigm_f(float x) {
    return 1.0f / (1.0f + __expf(-x));
}
__device__ __forceinline__ float tanh_f(float x) {
    return 1.0f - 2.0f / (__expf(2.0f * x) + 1.0f);
}

// Barrier draining only LDS (lgkmcnt), not vmcnt: hcat stores and the pre
// prefetch loads stay in flight across step boundaries.
__device__ __forceinline__ void bar_lds() {
    __builtin_amdgcn_sched_barrier(0);
    asm volatile("s_waitcnt lgkmcnt(0)" ::: "memory");
    __builtin_amdgcn_s_barrier();
    __builtin_amdgcn_sched_barrier(0);
}

// ---------------------------------------------------------------------------
// pre_gemm: pre[d][m][gtype*GP + hid] = sum_k A[m][k]*wih_d[gtype*H+hid][k]+b
// (unchanged from round 6 -- layout verified correct)
// ---------------------------------------------------------------------------
__global__ __launch_bounds__(256) void pre_gemm(
    const float* __restrict__ A,
    const float* __restrict__ wf, const float* __restrict__ wb,
    const float* __restrict__ bif, const float* __restrict__ bhf,
    const float* __restrict__ bib, const float* __restrict__ bhb,
    __half* __restrict__ pre)            // [2][M_TOT][PR4]
{
    const int BM = 64, BN = 64, BK = 16;
    int m0 = blockIdx.x * BM;
    int n0 = blockIdx.y * BN;
    __shared__ float As[BK][BM + 1];
    __shared__ float Bs[BK][BN + 1];
    int tid = threadIdx.x;
    int tx = tid & 15, ty = tid >> 4;
    float acc[4][4] = {};

    for (int k0 = 0; k0 < H; k0 += BK) {
        #pragma unroll
        for (int l = 0; l < (BM * BK) / 256; ++l) {
            int e = tid + l * 256;
            int mm = e / BK, kk = e % BK;
            int k = k0 + kk;
            As[kk][mm] = (k < H) ? A[(size_t)(m0 + mm) * H + k] : 0.f;
        }
        #pragma unroll
        for (int l = 0; l < (BN * BK) / 256; ++l) {
            int e = tid + l * 256;
            int nn = e / BK, kk = e % BK;
            int n = n0 + nn, k = k0 + kk;
            float v = 0.f;
            if (k < H && n < 2 * G4)
                v = (n < G4) ? wf[(size_t)n * H + k] : wb[(size_t)(n - G4) * H + k];
            Bs[kk][nn] = v;
        }
        __syncthreads();
        #pragma unroll
        for (int kk = 0; kk < BK; ++kk) {
            float a4[4], b4[4];
            #pragma unroll
            for (int i = 0; i < 4; ++i) a4[i] = As[kk][ty + 16 * i];
            #pragma unroll
            for (int j = 0; j < 4; ++j) b4[j] = Bs[kk][tx + 16 * j];
            #pragma unroll
            for (int i = 0; i < 4; ++i)
                #pragma unroll
                for (int j = 0; j < 4; ++j) acc[i][j] += a4[i] * b4[j];
        }
        __syncthreads();
    }

    #pragma unroll
    for (int i = 0; i < 4; ++i) {
        int m = m0 + ty + 16 * i;
        #pragma unroll
        for (int j = 0; j < 4; ++j) {
            int n = n0 + tx + 16 * j;
            if (n < 2 * G4) {
                int d = (n >= G4) ? 1 : 0;
                int g = n - d * G4;                  // gate-major 0..643
                int gtype = g / H;
                int hid = g - gtype * H;
                float bias = d ? (bib[g] + bhb[g]) : (bif[g] + bhf[g]);
                pre[(size_t)(d * M_TOT + m) * PR4 + gtype * GP + hid] =
                    __float2half(acc[i][j] + bias);
            }
        }
    }
}

// ---------------------------------------------------------------------------
// lstm_scan v7: 64 blocks = (32 batch x 2 dir), 704 threads = 11 waves.
// Wave w owns hid-tile w (16 hids). Per step: gates = [644 x 192].h via
// mfma_f32_16x16x32_f16, 24 MFMA/wave. Weights = MFMA A-operands (AGPR-
// native, no VALU-read tax: round 6 proved this spill-free at VGPR=84).
// B operand is a BROADCAST column: all 16 lanes of a k-group read the SAME
// h fragment (wave-uniform ds_read_b128, zero bank conflicts), so all 16
// C columns hold identical gate values -> every lane updates its 4 hids
// redundantly, no cross-lane exchange. C mapping (lane hg=l>>4, reg r ->
// hid w*16+hg*4+r) verified by round 6's numeric pass.
// pre loads and hcat stores are wave-uniform / contiguous (round 6's killer
// was batch-major scatter: 16 cache lines per wave-load).
// One lgkm-only barrier per step; h double-buffered (800 B LDS);
// pre prefetched 2 steps deep across the barrier.
// ---------------------------------------------------------------------------
__global__ __launch_bounds__(704, 3) void lstm_scan(
    const __half* __restrict__ pre,      // [2][M_TOT][PR4]
    const float* __restrict__ whh_f,
    const float* __restrict__ whh_b,
    float* __restrict__ hcat)            // [M_TOT][2*H]
{
    const int b = blockIdx.x;            // 0..31
    const int d = blockIdx.y;            // 0,1
    const int tid = threadIdx.x;
    const int w = tid >> 6;              // wave 0..10 (hid-tile)
    const int l = tid & 63;
    const int bl = l & 15;               // A-row-in-tile / C column
    const int hg = l >> 4;               // k-group for B, hid-group for C
    const float* whh = d ? whh_b : whh_f;

    __shared__ __align__(16) __half h_sh[2][KS2];     // 800 B

    // ---- A fragments: rows = whh[g*H + w*16+bl], k = kt*32 + hg*8 + j.
    const int hid0 = w * 16 + bl;
    const bool rowok = (hid0 < H);
    const int hid0c = rowok ? hid0 : (H - 1);
    f16x8 af[4][6];
    #pragma unroll
    for (int g = 0; g < 4; ++g) {
        const float* row = whh + ((size_t)g * H + hid0c) * H;
        #pragma unroll
        for (int kt = 0; kt < 6; ++kt) {
            f16x8 v;
            #pragma unroll
            for (int j = 0; j < 8; ++j) {
                int k = kt * 32 + hg * 8 + j;
                int kc = (k < H) ? k : (H - 1);
                float x = row[kc];
                v[j] = (_Float16)((rowok && k < H) ? x : 0.f);
            }
            af[g][kt] = v;
        }
    }

    // zero both h buffers (k-pad 161..191 must stay zero forever)
    if (tid < KS2) { h_sh[0][tid] = __half(0.f); h_sh[1][tid] = __half(0.f); }

    float c[4] = {0.f, 0.f, 0.f, 0.f};
    const int hb = w * 16 + hg * 4;                  // lane's first hid
    const int hbc = (hb <= 160) ? hb : 156;          // clamp pad lanes in-plane
    const __half* pb0 = pre + ((size_t)d * M_TOT + (size_t)b * TT) * PR4 + hbc;

    struct PreQ { uint2 gi, gf, gg, go; };
    #define LDP(tt_) ({                                                      \
        int tc_ = ((tt_) < TT) ? (tt_) : (TT - 1);                           \
        int t_  = d ? (TT - 1 - tc_) : tc_;                                  \
        const __half* pp_ = pb0 + (size_t)t_ * PR4;                          \
        PreQ r_;                                                             \
        r_.gi = *(const uint2*)(pp_);                                        \
        r_.gf = *(const uint2*)(pp_ + GP);                                   \
        r_.gg = *(const uint2*)(pp_ + 2 * GP);                               \
        r_.go = *(const uint2*)(pp_ + 3 * GP);                               \
        r_; })

    PreQ pA = LDP(0), pB = LDP(1);
    __syncthreads();

    #define SCAN_STEP(TTT, PJ, RB) {                                         \
        PreQ pc = PJ;                                                        \
        PJ = LDP((TTT) + 2);              /* 2-steps-ahead prefetch */       \
        f16x8 bfr[6];                                                        \
        _Pragma("unroll")                                                    \
        for (int kt = 0; kt < 6; ++kt)                                       \
            bfr[kt] = *(const f16x8*)&h_sh[RB][kt * 32 + hg * 8];            \
        f32x4 zz = {0.f, 0.f, 0.f, 0.f};                                     \
        f32x4 ci = zz, cf = zz, cg = zz, co = zz;                            \
        _Pragma("unroll")                                                    \
        for (int kt = 0; kt < 6; ++kt) {                                     \
            ci = __builtin_amdgcn_mfma_f32_16x16x32_f16(                     \
                af[0][kt], bfr[kt], ci, 0, 0, 0);                            \
            cf = __builtin_amdgcn_mfma_f32_16x16x32_f16(                     \
                af[1][kt], bfr[kt], cf, 0, 0, 0);                            \
            cg = __builtin_amdgcn_mfma_f32_16x16x32_f16(                     \
                af[2][kt], bfr[kt], cg, 0, 0, 0);                            \
            co = __builtin_amdgcn_mfma_f32_16x16x32_f16(                     \
                af[3][kt], bfr[kt], co, 0, 0, 0);                            \
        }                                                                    \
        float pi[4], pf[4], pg[4], po[4];                                    \
        { h2_t u0 = bc_h2(pc.gi.x), u1 = bc_h2(pc.gi.y);                     \
          pi[0] = (float)u0[0]; pi[1] = (float)u0[1];                        \
          pi[2] = (float)u1[0]; pi[3] = (float)u1[1]; }                      \
        { h2_t u0 = bc_h2(pc.gf.x), u1 = bc_h2(pc.gf.y);                     \
          pf[0] = (float)u0[0]; pf[1] = (float)u0[1];                        \
          pf[2] = (float)u1[0]; pf[3] = (float)u1[1]; }                      \
        { h2_t u0 = bc_h2(pc.gg.x), u1 = bc_h2(pc.gg.y);                     \
          pg[0] = (float)u0[0]; pg[1] = (float)u0[1];                        \
          pg[2] = (float)u1[0]; pg[3] = (float)u1[1]; }                      \
        { h2_t u0 = bc_h2(pc.go.x), u1 = bc_h2(pc.go.y);                     \
          po[0] = (float)u0[0]; po[1] = (float)u0[1];                        \
          po[2] = (float)u1[0]; po[3] = (float)u1[1]; }                      \
        float hv[4];                                                         \
        _Pragma("unroll")                                                    \
        for (int r = 0; r < 4; ++r) {                                        \
            float iv = sigm_f(ci[r] + pi[r]);                                \
            float fv = sigm_f(cf[r] + pf[r]);                                \
            float gv = tanh_f(cg[r] + pg[r]);                                \
            float ov = sigm_f(co[r] + po[r]);                                \
            c[r] = fv * c[r] + iv * gv;                                      \
            hv[r] = ov * tanh_f(c[r]);                                       \
        }                                                                    \
        int t = d ? (TT - 1 - (TTT)) : (TTT);                                \
        size_t hrow = ((size_t)b * TT + t) * (2 * H) + (size_t)d * H;        \
        if (bl == 0) {                                                       \
            _Pragma("unroll")                                                \
            for (int r = 0; r < 4; ++r) {                                    \
                if (hb + r < H) {                                            \
                    hcat[hrow + hb + r] = hv[r];                             \
                    h_sh[(RB) ^ 1][hb + r] = __float2half(hv[r]);            \
                }                                                            \
            }                                                                \
        }                                                                    \
        bar_lds();                                                           \
    }

    for (int base = 0; base < TT; base += 2) {
        SCAN_STEP(base,     pA, 0)
        SCAN_STEP(base + 1, pB, 1)
    }
    #undef SCAN_STEP
    #undef LDP
}

// ---------------------------------------------------------------------------
// lin_gemm: out[m][n] = relu?(sum_k hcat[m][k]*W[n][k] + bl[n]) + res[m][n]
// ---------------------------------------------------------------------------
__global__ __launch_bounds__(256) void lin_gemm(
    const float* __restrict__ A,     // [M_TOT][2H]
    const float* __restrict__ W,     // [H][2H]
    const float* __restrict__ bl,    // [H]
    const float* __restrict__ res,   // [M_TOT][H]
    float* __restrict__ out,         // [M_TOT][H]
    int relu)
{
    const int BM = 64, BN = 64, BK = 16;
    const int K = 2 * H;
    int m0 = blockIdx.x * BM;
    int n0 = blockIdx.y * BN;
    __shared__ float As[BK][BM + 1];
    __shared__ float Bs[BK][BN + 1];
    int tid = threadIdx.x;
    int tx = tid & 15, ty = tid >> 4;
    float acc[4][4] = {};

    for (int k0 = 0; k0 < K; k0 += BK) {
        #pragma unroll
        for (int l = 0; l < (BM * BK) / 256; ++l) {
            int e = tid + l * 256;
            int mm = e / BK, kk = e % BK;
            int k = k0 + kk;
            As[kk][mm] = (k < K) ? A[(size_t)(m0 + mm) * K + k] : 0.f;
        }
        #pragma unroll
        for (int l = 0; l < (BN * BK) / 256; ++l) {
            int e = tid + l * 256;
            int nn = e / BK, kk = e % BK;
            int n = n0 + nn, k = k0 + kk;
            Bs[kk][nn] = (k < K && n < H) ? W[(size_t)n * K + k] : 0.f;
        }
        __syncthreads();
        #pragma unroll
        for (int kk = 0; kk < BK; ++kk) {
            float a4[4], b4[4];
            #pragma unroll
            for (int i = 0; i < 4; ++i) a4[i] = As[kk][ty + 16 * i];
            #pragma unroll
            for (int j = 0; j < 4; ++j) b4[j] = Bs[kk][tx + 16 * j];
            #pragma unroll
            for (int i = 0; i < 4; ++i)
                #pragma unroll
                for (int j = 0; j < 4; ++j) acc[i][j] += a4[i] * b4[j];
        }
        __syncthreads();
    }

    #pragma unroll
    for (int i = 0; i < 4; ++i) {
        int m = m0 + ty + 16 * i;
        #pragma unroll
        for (int j = 0; j < 4; ++j) {
            int n = n0 + tx + 16 * j;
            if (n < H) {
                float v = acc[i][j] + bl[n];
                if (relu) v = fmaxf(v, 0.f);
                v += res[(size_t)m * H + n];
                out[(size_t)m * H + n] = v;
            }
        }
    }
}

extern "C" void kernel_launch(void* const* d_in, const int* in_sizes, int n_in,
                              void* d_out, int out_size, void* d_ws, size_t ws_size,
                              hipStream_t stream) {
    const float* x = (const float*)d_in[0];

    char* ws = (char*)d_ws;
    __half* pre = (__half*)ws;                       // 2*32000*656*2 B = 84 MB
    float* hcat = (float*)(ws + (size_t)2 * M_TOT * PR4 * sizeof(__half));
    float* bufB = hcat + (size_t)M_TOT * 2 * H;      // 20.6 MB
    // d_out doubles as the layer-1 output buffer.

    const float* cur = x;
    float* outs[3] = {(float*)d_out, bufB, (float*)d_out};

    for (int l = 0; l < 3; ++l) {
        const float* const* p = (const float* const*)(d_in + 1 + 10 * l);
        // p: wih_f whh_f bih_f bhh_f wih_b whh_b bih_b bhh_b W bl
        dim3 g1(M_TOT / 64, 21);
        pre_gemm<<<g1, 256, 0, stream>>>(cur, p[0], p[4], p[2], p[3], p[6], p[7], pre);
        lstm_scan<<<dim3(32, 2), 704, 0, stream>>>(pre, p[1], p[5], hcat);
        dim3 g2(M_TOT / 64, 3);
        lin_gemm<<<g2, 256, 0, stream>>>(hcat, p[8], p[9], cur, outs[l], (l < 2) ? 1 : 0);
        cur = outs[l];
    }
}

// Round 9
// 4454.370 us; speedup vs baseline: 2.0565x; 2.0565x over previous
//
#include <hip/hip_runtime.h>
#include <hip/hip_fp16.h>

#define H 161
#define H2 322            // 2*H = pair offset (lane L owns gates L and L+322)
#define G4 644            // 4*H gates
#define BB 32             // batch
#define TT 1000           // time
#define M_TOT (BB*TT)     // 32000 rows
#define KP2 84            // half2 pairs per gate row (K padded to 168)

typedef _Float16 h2_t __attribute__((ext_vector_type(2)));

__device__ __forceinline__ h2_t bc_h2(unsigned int u) {
    return __builtin_bit_cast(h2_t, u);
}

__device__ __forceinline__ float dot2f(h2_t a, h2_t b, float c) {
#if __has_builtin(__builtin_amdgcn_fdot2)
    return __builtin_amdgcn_fdot2(a, b, c, false);
#else
    return c + (float)a[0] * (float)b[0] + (float)a[1] * (float)b[1];
#endif
}

__device__ __forceinline__ float sigm_f(float x) {
    return 1.0f / (1.0f + __expf(-x));
}
__device__ __forceinline__ float tanh_f(float x) {
    return 1.0f - 2.0f / (__expf(2.0f * x) + 1.0f);
}

// Barrier draining only LDS (lgkmcnt), not vmcnt: hcat stores and pre
// prefetch loads stay in flight across step boundaries.
__device__ __forceinline__ void bar_lds() {
    __builtin_amdgcn_sched_barrier(0);
    asm volatile("s_waitcnt lgkmcnt(0)" ::: "memory");
    __builtin_amdgcn_s_barrier();
    __builtin_amdgcn_sched_barrier(0);
}

// ---------------------------------------------------------------------------
// pre_gemm (identical to round 5's verified version): pair layout
// pre2[d][m][L] = uint packing halfs (pre[gate L], pre[gate L+322]), L<322.
// lstm_scan lane L loads its two pre values with ONE coalesced 4-byte read.
// ---------------------------------------------------------------------------
__global__ __launch_bounds__(256) void pre_gemm(
    const float* __restrict__ A,
    const float* __restrict__ wf, const float* __restrict__ wb,
    const float* __restrict__ bif, const float* __restrict__ bhf,
    const float* __restrict__ bib, const float* __restrict__ bhb,
    __half* __restrict__ pre2)           // [2][M_TOT][322] uint pairs, as half*
{
    const int BM = 64, BN = 64, BK = 16;
    int m0 = blockIdx.x * BM;
    int n0 = blockIdx.y * BN;
    __shared__ float As[BK][BM + 1];
    __shared__ float Bs[BK][BN + 1];
    int tid = threadIdx.x;
    int tx = tid & 15, ty = tid >> 4;
    float acc[4][4] = {};

    for (int k0 = 0; k0 < H; k0 += BK) {
        #pragma unroll
        for (int l = 0; l < (BM * BK) / 256; ++l) {
            int e = tid + l * 256;
            int mm = e / BK, kk = e % BK;
            int k = k0 + kk;
            As[kk][mm] = (k < H) ? A[(size_t)(m0 + mm) * H + k] : 0.f;
        }
        #pragma unroll
        for (int l = 0; l < (BN * BK) / 256; ++l) {
            int e = tid + l * 256;
            int nn = e / BK, kk = e % BK;
            int n = n0 + nn, k = k0 + kk;
            float v = 0.f;
            if (k < H && n < 2 * G4)
                v = (n < G4) ? wf[(size_t)n * H + k] : wb[(size_t)(n - G4) * H + k];
            Bs[kk][nn] = v;
        }
        __syncthreads();
        #pragma unroll
        for (int kk = 0; kk < BK; ++kk) {
            float a4[4], b4[4];
            #pragma unroll
            for (int i = 0; i < 4; ++i) a4[i] = As[kk][ty + 16 * i];
            #pragma unroll
            for (int j = 0; j < 4; ++j) b4[j] = Bs[kk][tx + 16 * j];
            #pragma unroll
            for (int i = 0; i < 4; ++i)
                #pragma unroll
                for (int j = 0; j < 4; ++j) acc[i][j] += a4[i] * b4[j];
        }
        __syncthreads();
    }

    #pragma unroll
    for (int i = 0; i < 4; ++i) {
        int m = m0 + ty + 16 * i;
        #pragma unroll
        for (int j = 0; j < 4; ++j) {
            int n = n0 + tx + 16 * j;
            if (n < 2 * G4) {
                int d = (n >= G4) ? 1 : 0;
                int g = n - d * G4;                  // gate-major 0..643
                int L    = (g < H2) ? g : (g - H2);  // pair lane
                int slot = (g < H2) ? 0 : 1;
                float bias = d ? (bib[g] + bhb[g]) : (bif[g] + bhf[g]);
                pre2[(((size_t)d * M_TOT + m) * H2 + L) * 2 + slot] =
                    __float2half(acc[i][j] + bias);
            }
        }
    }
}

// ---------------------------------------------------------------------------
// lstm_scan v8: round 5's verified structure (384 thr, 2 gates/lane, gsh
// f/o exchange, pair-packed pre, 2-step prefetch) with ONE change: the h
// broadcast is round 1's verified 21x uint4 LDS read loop instead of 84
// v_readlane's (whose SGPR-write->VALU-read hazard cost ~1700 cyc/step,
// measured R5 vs model). 6 waves x 21 ds_read_b128 ~= 1000 cyc/step LDS
// (vs 1850 at 11 waves in R1 -- the measured R1 bottleneck).
// Dot chains split 4-way (42 deep) to cap dependent-fdot2 latency.
// MFMA rejected by measurement: R6/R8 both ~6300 cyc/step regardless of
// memory hygiene -- structural serial floor at matvec granularity.
// ---------------------------------------------------------------------------
__global__ __launch_bounds__(384, 1) void lstm_scan(
    const unsigned int* __restrict__ pre2,   // [2][M_TOT][322] packed pairs
    const float* __restrict__ whh_f,
    const float* __restrict__ whh_b,
    float* __restrict__ hcat)                // [M_TOT][2*H]
{
    const int b = blockIdx.x;            // 0..31
    const int d = blockIdx.y;            // 0,1
    const int tid = threadIdx.x;
    const float* whh = d ? whh_b : whh_f;

    __shared__ __align__(16) unsigned int h_sh[KP2];   // 168 halves = 21 uint4
    __shared__ float2 gsh[H];                          // (fg, og) per hid

    const bool active = tid < H2;
    const int L = active ? tid : (H2 - 1);            // clamp lanes 322..383
    const bool low = (L < H);                          // i/g lane (owns hid L)

    // Two weight rows, packed half2, K padded to 168.
    unsigned int w0[KP2], w1[KP2];
    {
        const float* r0 = whh + (size_t)L * H;         // rows 0..321 = i,f
        const float* r1 = whh + (size_t)(L + H2) * H;  // rows 322..643 = g,o
        #pragma unroll
        for (int i = 0; i < KP2; ++i) {
            int k = 2 * i;
            float a0 = (k < H) ? r0[k] : 0.f;
            float a1 = (k + 1 < H) ? r0[k + 1] : 0.f;
            float b0 = (k < H) ? r1[k] : 0.f;
            float b1 = (k + 1 < H) ? r1[k + 1] : 0.f;
            h2_t v0; v0[0] = (_Float16)a0; v0[1] = (_Float16)a1;
            h2_t v1; v1[0] = (_Float16)b0; v1[1] = (_Float16)b1;
            w0[i] = __builtin_bit_cast(unsigned int, v0);
            w1[i] = __builtin_bit_cast(unsigned int, v1);
        }
    }
    if (tid < KP2) h_sh[tid] = 0u;

    float c = 0.f;
    const unsigned int* pb = pre2 + ((size_t)d * M_TOT + (size_t)b * TT) * H2 + L;

    #define LDP(tt_) ({ int tc_ = ((tt_) < TT) ? (tt_) : (TT - 1);          \
                        int t_  = d ? (TT - 1 - tc_) : tc_;                 \
                        pb[(size_t)t_ * H2]; })

    unsigned int p0 = LDP(0), p1 = LDP(1);
    __syncthreads();

    #define STEP(TTT, PJ) {                                                 \
        int t = d ? (TT - 1 - (TTT)) : (TTT);                               \
        h2_t pp = bc_h2(PJ);                                                \
        float a0 = (float)pp[0], a0b = 0.f;                                 \
        float a1 = (float)pp[1], a1b = 0.f;                                 \
        PJ = LDP((TTT) + 2);            /* 2-steps-ahead prefetch */        \
        const uint4* h4 = (const uint4*)h_sh;                               \
        _Pragma("unroll")                                                   \
        for (int i = 0; i < 21; ++i) {                                      \
            uint4 hh = h4[i];                                               \
            h2_t hx = bc_h2(hh.x), hy = bc_h2(hh.y);                        \
            h2_t hz = bc_h2(hh.z), hw = bc_h2(hh.w);                        \
            a0  = dot2f(bc_h2(w0[4*i+0]), hx, a0);                          \
            a0b = dot2f(bc_h2(w0[4*i+1]), hy, a0b);                         \
            a0  = dot2f(bc_h2(w0[4*i+2]), hz, a0);                          \
            a0b = dot2f(bc_h2(w0[4*i+3]), hw, a0b);                         \
            a1  = dot2f(bc_h2(w1[4*i+0]), hx, a1);                          \
            a1b = dot2f(bc_h2(w1[4*i+1]), hy, a1b);                         \
            a1  = dot2f(bc_h2(w1[4*i+2]), hz, a1);                          \
            a1b = dot2f(bc_h2(w1[4*i+3]), hw, a1b);                         \
        }                                                                   \
        a0 += a0b; a1 += a1b;                                               \
        float act0 = sigm_f(a0);                 /* i (low) or f (high) */  \
        float xs = low ? (a1 + a1) : a1;                                    \
        float ss = sigm_f(xs);                                              \
        float act1 = low ? (ss + ss - 1.0f) : ss; /* g=tanh or o=sigm */    \
        if (active && !low) gsh[L - H] = make_float2(act0, act1);           \
        bar_lds();                                                          \
        if (tid < H) {                                                      \
            float2 fo = gsh[tid];                 /* (fg, og) */            \
            c = fo.x * c + act0 * act1;           /* own ig, gg */          \
            float hval = fo.y * tanh_f(c);                                  \
            hcat[((size_t)b * TT + t) * (2 * H) + (size_t)d * H + tid] = hval; \
            ((__half*)h_sh)[tid] = __float2half(hval);                      \
        }                                                                   \
        bar_lds();                                                          \
    }

    for (int base = 0; base < TT; base += 2) {
        STEP(base,     p0)
        STEP(base + 1, p1)
    }
    #undef STEP
    #undef LDP
}

// ---------------------------------------------------------------------------
// lin_gemm: out[m][n] = relu?(sum_k hcat[m][k]*W[n][k] + bl[n]) + res[m][n]
// ---------------------------------------------------------------------------
__global__ __launch_bounds__(256) void lin_gemm(
    const float* __restrict__ A,     // [M_TOT][2H]
    const float* __restrict__ W,     // [H][2H]
    const float* __restrict__ bl,    // [H]
    const float* __restrict__ res,   // [M_TOT][H]
    float* __restrict__ out,         // [M_TOT][H]
    int relu)
{
    const int BM = 64, BN = 64, BK = 16;
    const int K = 2 * H;
    int m0 = blockIdx.x * BM;
    int n0 = blockIdx.y * BN;
    __shared__ float As[BK][BM + 1];
    __shared__ float Bs[BK][BN + 1];
    int tid = threadIdx.x;
    int tx = tid & 15, ty = tid >> 4;
    float acc[4][4] = {};

    for (int k0 = 0; k0 < K; k0 += BK) {
        #pragma unroll
        for (int l = 0; l < (BM * BK) / 256; ++l) {
            int e = tid + l * 256;
            int mm = e / BK, kk = e % BK;
            int k = k0 + kk;
            As[kk][mm] = (k < K) ? A[(size_t)(m0 + mm) * K + k] : 0.f;
        }
        #pragma unroll
        for (int l = 0; l < (BN * BK) / 256; ++l) {
            int e = tid + l * 256;
            int nn = e / BK, kk = e % BK;
            int n = n0 + nn, k = k0 + kk;
            Bs[kk][nn] = (k < K && n < H) ? W[(size_t)n * K + k] : 0.f;
        }
        __syncthreads();
        #pragma unroll
        for (int kk = 0; kk < BK; ++kk) {
            float a4[4], b4[4];
            #pragma unroll
            for (int i = 0; i < 4; ++i) a4[i] = As[kk][ty + 16 * i];
            #pragma unroll
            for (int j = 0; j < 4; ++j) b4[j] = Bs[kk][tx + 16 * j];
            #pragma unroll
            for (int i = 0; i < 4; ++i)
                #pragma unroll
                for (int j = 0; j < 4; ++j) acc[i][j] += a4[i] * b4[j];
        }
        __syncthreads();
    }

    #pragma unroll
    for (int i = 0; i < 4; ++i) {
        int m = m0 + ty + 16 * i;
        #pragma unroll
        for (int j = 0; j < 4; ++j) {
            int n = n0 + tx + 16 * j;
            if (n < H) {
                float v = acc[i][j] + bl[n];
                if (relu) v = fmaxf(v, 0.f);
                v += res[(size_t)m * H + n];
                out[(size_t)m * H + n] = v;
            }
        }
    }
}

extern "C" void kernel_launch(void* const* d_in, const int* in_sizes, int n_in,
                              void* d_out, int out_size, void* d_ws, size_t ws_size,
                              hipStream_t stream) {
    const float* x = (const float*)d_in[0];

    char* ws = (char*)d_ws;
    __half* pre2 = (__half*)ws;          // 2*32000*322 uints = 82.4 MB
    float* hcat = (float*)(ws + (size_t)2 * M_TOT * H2 * sizeof(unsigned int));
    float* bufA = hcat + (size_t)M_TOT * 2 * H;
    float* bufB = bufA + (size_t)M_TOT * H;

    const float* cur = x;
    float* outs[3] = {bufA, bufB, (float*)d_out};

    for (int l = 0; l < 3; ++l) {
        const float* const* p = (const float* const*)(d_in + 1 + 10 * l);
        // p: wih_f whh_f bih_f bhh_f wih_b whh_b bih_b bhh_b W bl
        dim3 g1(M_TOT / 64, 21);
        pre_gemm<<<g1, 256, 0, stream>>>(cur, p[0], p[4], p[2], p[3], p[6], p[7], pre2);
        lstm_scan<<<dim3(32, 2), 384, 0, stream>>>((const unsigned int*)pre2,
                                                   p[1], p[5], hcat);
        dim3 g2(M_TOT / 64, 3);
        lin_gemm<<<g2, 256, 0, stream>>>(hcat, p[8], p[9], cur, outs[l], (l < 2) ? 1 : 0);
        cur = outs[l];
    }
}

// Round 10
// 3597.931 us; speedup vs baseline: 2.5460x; 1.2380x over previous
//
#include <hip/hip_runtime.h>
#include <hip/hip_fp16.h>

#define H 161
#define G4 644            // 4*H gates
#define BB 32             // batch
#define TT 1000           // time
#define M_TOT (BB*TT)     // 32000 rows
#define KXP 192           // padded K for pre GEMM (161 data + 1 bias + pad0)
#define KLP 352           // padded K for lin GEMM (322 data + pad0)
#define NWIH 1344         // padded N of wih16 (21 * 64)
#define NPAIR 84          // half2 pairs covering K padded to 168 (scan)
#define NVEC (NPAIR/4)    // 21 uint4 reads of the h vector (scan)

typedef _Float16 h2_t  __attribute__((ext_vector_type(2)));
typedef _Float16 f16x8 __attribute__((ext_vector_type(8)));
typedef float    f32x4 __attribute__((ext_vector_type(4)));

__device__ __forceinline__ h2_t bc_h2(unsigned int u) {
    return __builtin_bit_cast(h2_t, u);
}

__device__ __forceinline__ float dot2f(h2_t a, h2_t b, float c) {
#if __has_builtin(__builtin_amdgcn_fdot2)
    return __builtin_amdgcn_fdot2(a, b, c, false);
#else
    return c + (float)a[0] * (float)b[0] + (float)a[1] * (float)b[1];
#endif
}

__device__ __forceinline__ float tanh_f(float x) {
    return 1.0f - 2.0f / (__expf(2.0f * x) + 1.0f);
}

// Barrier draining only LDS (lgkmcnt), not vmcnt.
__device__ __forceinline__ void bar_lds() {
    __builtin_amdgcn_sched_barrier(0);
    asm volatile("s_waitcnt lgkmcnt(0)" ::: "memory");
    __builtin_amdgcn_s_barrier();
    __builtin_amdgcn_sched_barrier(0);
}

// ---------------------------------------------------------------------------
// Convert kernels: pad + fp16-ify GEMM operands once per layer (tiny cost).
// Bias is baked in as k=161 (x column = 1.0, wih16 column = bias sum), so
// the MFMA k-loop is branch-free with zero padding.
// ---------------------------------------------------------------------------
__global__ __launch_bounds__(256) void cvt_x(
    const float* __restrict__ in,    // [M][161] fp32
    __half* __restrict__ out)        // [M][192] fp16
{
    const int total = M_TOT * KXP;
    for (int idx = blockIdx.x * 256 + threadIdx.x; idx < total;
         idx += gridDim.x * 256) {
        int m = idx / KXP, k = idx - m * KXP;
        float v = (k < H) ? in[(size_t)m * H + k] : (k == H ? 1.f : 0.f);
        out[idx] = __float2half(v);
    }
}

__global__ __launch_bounds__(256) void cvt_wih(
    const float* __restrict__ wf, const float* __restrict__ wb,
    const float* __restrict__ bif, const float* __restrict__ bhf,
    const float* __restrict__ bib, const float* __restrict__ bhb,
    __half* __restrict__ out)        // [1344][192] fp16
{
    const int total = NWIH * KXP;
    for (int idx = blockIdx.x * 256 + threadIdx.x; idx < total;
         idx += gridDim.x * 256) {
        int n = idx / KXP, k = idx - n * KXP;
        float v = 0.f;
        if (n < G4) {
            v = (k < H) ? wf[(size_t)n * H + k]
                        : (k == H ? bif[n] + bhf[n] : 0.f);
        } else if (n < 2 * G4) {
            int g = n - G4;
            v = (k < H) ? wb[(size_t)g * H + k]
                        : (k == H ? bib[g] + bhb[g] : 0.f);
        }
        out[idx] = __float2half(v);
    }
}

__global__ __launch_bounds__(256) void cvt_W(
    const float* __restrict__ W,     // [161][322] fp32
    __half* __restrict__ out)        // [192][352] fp16
{
    const int total = 192 * KLP;
    for (int idx = blockIdx.x * 256 + threadIdx.x; idx < total;
         idx += gridDim.x * 256) {
        int n = idx / KLP, k = idx - n * KLP;
        float v = (n < H && k < 2 * H) ? W[(size_t)n * (2 * H) + k] : 0.f;
        out[idx] = __float2half(v);
    }
}

// ---------------------------------------------------------------------------
// pre_mfma: pre[d][m][g] = wih16[n=d*G4+g][0:162] . A16[m][0:162]  (fp16 MFMA)
// Direct-from-global fragments, no LDS. Fragment mapping is the R6/R8-
// verified one: A-op row = lane&15, k = (lane>>4)*8+j; D row = (lane>>4)*4+r,
// col = lane&15. 4 waves (2m x 2n), each 32x32 out, BK=32, 6 k-tiles.
// ---------------------------------------------------------------------------
__global__ __launch_bounds__(256) void pre_mfma(
    const __half* __restrict__ A16,    // [M][192]
    const __half* __restrict__ Wih16,  // [1344][192]
    __half* __restrict__ pre)          // [2][M_TOT][644]
{
    const int m0 = blockIdx.x * 64, n0 = blockIdx.y * 64;
    const int tid = threadIdx.x;
    const int wv = tid >> 6, l = tid & 63;
    const int wm = wv & 1, wn = wv >> 1;
    const int cl = l & 15, kg = l >> 4;

    const __half* ap = A16   + (size_t)(m0 + wm * 32 + cl) * KXP + kg * 8;
    const __half* wp = Wih16 + (size_t)(n0 + wn * 32 + cl) * KXP + kg * 8;

    f32x4 acc[2][2] = {};
    #pragma unroll
    for (int kt = 0; kt < 6; ++kt) {
        f16x8 w0 = *(const f16x8*)(wp + kt * 32);
        f16x8 w1 = *(const f16x8*)(wp + 16 * KXP + kt * 32);
        f16x8 x0 = *(const f16x8*)(ap + kt * 32);
        f16x8 x1 = *(const f16x8*)(ap + 16 * KXP + kt * 32);
        acc[0][0] = __builtin_amdgcn_mfma_f32_16x16x32_f16(w0, x0, acc[0][0], 0, 0, 0);
        acc[0][1] = __builtin_amdgcn_mfma_f32_16x16x32_f16(w0, x1, acc[0][1], 0, 0, 0);
        acc[1][0] = __builtin_amdgcn_mfma_f32_16x16x32_f16(w1, x0, acc[1][0], 0, 0, 0);
        acc[1][1] = __builtin_amdgcn_mfma_f32_16x16x32_f16(w1, x1, acc[1][1], 0, 0, 0);
    }

    #pragma unroll
    for (int sn = 0; sn < 2; ++sn)
        #pragma unroll
        for (int sm = 0; sm < 2; ++sm) {
            int n = n0 + wn * 32 + sn * 16 + kg * 4;   // 4 consecutive n
            int m = m0 + wm * 32 + sm * 16 + cl;
            if (n < 2 * G4) {                          // groups never straddle
                int d = (n >= G4) ? 1 : 0;
                int g = n - d * G4;
                __half2 lo, hi;
                lo.x = __float2half(acc[sn][sm][0]);
                lo.y = __float2half(acc[sn][sm][1]);
                hi.x = __float2half(acc[sn][sm][2]);
                hi.y = __float2half(acc[sn][sm][3]);
                __half* dst = pre + ((size_t)d * M_TOT + m) * G4 + g;
                *(__half2*)dst = lo;
                *(__half2*)(dst + 2) = hi;
            }
        }
}

// ---------------------------------------------------------------------------
// lin_mfma: out[m][n] = relu?(W16[n][:].Hc[m][:] + bl[n]) + res[m][n]
// Same structure; K=322 padded to 352 (11 k-tiles), N=161 over 3 n-tiles.
// ---------------------------------------------------------------------------
__global__ __launch_bounds__(256) void lin_mfma(
    const __half* __restrict__ Hc,     // [M][352] fp16 (scan output, pad0)
    const __half* __restrict__ W16,    // [192][352]
    const float* __restrict__ bl,      // [161]
    const float* __restrict__ res,     // [M][161] fp32
    float* __restrict__ out,           // [M][161] fp32
    int relu)
{
    const int m0 = blockIdx.x * 64, n0 = blockIdx.y * 64;
    const int tid = threadIdx.x;
    const int wv = tid >> 6, l = tid & 63;
    const int wm = wv & 1, wn = wv >> 1;
    const int cl = l & 15, kg = l >> 4;

    const __half* ap = Hc  + (size_t)(m0 + wm * 32 + cl) * KLP + kg * 8;
    const __half* wp = W16 + (size_t)(n0 + wn * 32 + cl) * KLP + kg * 8;

    f32x4 acc[2][2] = {};
    #pragma unroll
    for (int kt = 0; kt < 11; ++kt) {
        f16x8 w0 = *(const f16x8*)(wp + kt * 32);
        f16x8 w1 = *(const f16x8*)(wp + 16 * KLP + kt * 32);
        f16x8 x0 = *(const f16x8*)(ap + kt * 32);
        f16x8 x1 = *(const f16x8*)(ap + 16 * KLP + kt * 32);
        acc[0][0] = __builtin_amdgcn_mfma_f32_16x16x32_f16(w0, x0, acc[0][0], 0, 0, 0);
        acc[0][1] = __builtin_amdgcn_mfma_f32_16x16x32_f16(w0, x1, acc[0][1], 0, 0, 0);
        acc[1][0] = __builtin_amdgcn_mfma_f32_16x16x32_f16(w1, x0, acc[1][0], 0, 0, 0);
        acc[1][1] = __builtin_amdgcn_mfma_f32_16x16x32_f16(w1, x1, acc[1][1], 0, 0, 0);
    }

    #pragma unroll
    for (int sn = 0; sn < 2; ++sn)
        #pragma unroll
        for (int sm = 0; sm < 2; ++sm) {
            int nb = n0 + wn * 32 + sn * 16 + kg * 4;
            int m  = m0 + wm * 32 + sm * 16 + cl;
            #pragma unroll
            for (int r = 0; r < 4; ++r) {
                int n = nb + r;
                if (n < H) {
                    float v = acc[sn][sm][r] + bl[n];
                    if (relu) v = fmaxf(v, 0.f);
                    v += res[(size_t)m * H + n];
                    out[(size_t)m * H + n] = v;
                }
            }
        }
}

// ---------------------------------------------------------------------------
// lstm_scan: round 1's verified 1001 us kernel, unchanged except hcat is
// written as fp16 into the K-padded [M][352] buffer feeding lin_mfma.
// ---------------------------------------------------------------------------
__global__ __launch_bounds__(704, 3) void lstm_scan(
    const __half* __restrict__ pre,      // [2][M_TOT][G4]
    const float* __restrict__ whh_f,
    const float* __restrict__ whh_b,
    __half* __restrict__ hcat)           // [M_TOT][KLP] fp16
{
    const int b = blockIdx.x;            // 0..31
    const int d = blockIdx.y;            // 0,1
    const int tid = threadIdx.x;
    const float* whh = d ? whh_b : whh_f;

    __shared__ __align__(16) unsigned int h_sh[NPAIR];  // 168 halves
    __shared__ float gate_sh[G4];

    const bool active = tid < G4;
    h2_t w[NPAIR];
    if (active) {
        const float* row = whh + (size_t)tid * H;
        #pragma unroll
        for (int i = 0; i < NPAIR; ++i) {
            float w0 = (2 * i < H) ? row[2 * i] : 0.f;
            float w1 = (2 * i + 1 < H) ? row[2 * i + 1] : 0.f;
            h2_t v; v[0] = (_Float16)w0; v[1] = (_Float16)w1;
            w[i] = v;
        }
    }
    if (tid < NPAIR) h_sh[tid] = 0u;
    float c = 0.f;
    const __half* pb = pre + ((size_t)d * M_TOT + (size_t)b * TT) * G4;
    const bool is_g_gate = (tid >= 2 * H) && (tid < 3 * H);

    int t0 = d ? (TT - 1) : 0;
    __half pc = __half(0.0f);
    if (active) pc = pb[(long long)t0 * G4 + tid];
    __syncthreads();

    for (int ttt = 0; ttt < TT; ++ttt) {
        int t = d ? (TT - 1 - ttt) : ttt;
        // Prefetch next step's pre. Unclamped t+-1 stays inside the
        // [2][M_TOT][G4] buffer for every (b,d); final stale prefetch
        // is never consumed.
        int tn = d ? (t - 1) : (t + 1);
        __half pn = __half(0.0f);
        if (active) pn = pb[(long long)tn * G4 + tid];

        if (active) {
            float a0 = 0.f, a1 = 0.f, a2 = 0.f, a3 = 0.f;
            const uint4* hv = (const uint4*)h_sh;
            #pragma unroll
            for (int i = 0; i < NVEC; ++i) {
                uint4 hh = hv[i];
                a0 = dot2f(w[4 * i + 0], bc_h2(hh.x), a0);
                a1 = dot2f(w[4 * i + 1], bc_h2(hh.y), a1);
                a2 = dot2f(w[4 * i + 2], bc_h2(hh.z), a2);
                a3 = dot2f(w[4 * i + 3], bc_h2(hh.w), a3);
            }
            float acc = __half2float(pc) + (a0 + a1) + (a2 + a3);
            // Single-exp activation: tanh(x) = 2*sigmoid(2x) - 1.
            float xs = is_g_gate ? (acc + acc) : acc;
            float s = 1.0f / (1.0f + __expf(-xs));
            gate_sh[tid] = is_g_gate ? (s + s - 1.0f) : s;
        }
        bar_lds();
        if (tid < H) {
            float ig = gate_sh[tid];
            float fg = gate_sh[tid + H];
            float gg = gate_sh[tid + 2 * H];
            float og = gate_sh[tid + 3 * H];
            c = fg * c + ig * gg;
            float h = og * tanh_f(c);
            __half h16 = __float2half(h);
            hcat[((size_t)b * TT + t) * KLP + (size_t)d * H + tid] = h16;
            ((__half*)h_sh)[tid] = h16;
        }
        bar_lds();
        pc = pn;
    }
}

extern "C" void kernel_launch(void* const* d_in, const int* in_sizes, int n_in,
                              void* d_out, int out_size, void* d_ws, size_t ws_size,
                              hipStream_t stream) {
    const float* x = (const float*)d_in[0];

    char* ws = (char*)d_ws;
    __half* pre    = (__half*)ws;                                   // 82.4 MB
    __half* hcat16 = (__half*)(ws + (size_t)2 * M_TOT * G4 * 2);    // 22.5 MB
    __half* A16    = (__half*)((char*)hcat16 + (size_t)M_TOT * KLP * 2); // 12.3 MB
    __half* wih16  = (__half*)((char*)A16 + (size_t)M_TOT * KXP * 2);    // 0.5 MB
    __half* W16    = (__half*)((char*)wih16 + (size_t)NWIH * KXP * 2);   // 0.14 MB
    float*  bufA   = (float*)((char*)W16 + (size_t)192 * KLP * 2);       // 20.6 MB
    float*  bufB   = bufA + (size_t)M_TOT * H;                           // 20.6 MB

    // Zero hcat16 once: covers the k-pad (322..351) the scan never writes.
    hipMemsetAsync(hcat16, 0, (size_t)M_TOT * KLP * sizeof(__half), stream);

    const float* cur = x;
    float* outs[3] = {bufA, bufB, (float*)d_out};

    for (int l = 0; l < 3; ++l) {
        const float* const* p = (const float* const*)(d_in + 1 + 10 * l);
        // p: wih_f whh_f bih_f bhh_f wih_b whh_b bih_b bhh_b W bl
        cvt_x  <<<2048, 256, 0, stream>>>(cur, A16);
        cvt_wih<<<256, 256, 0, stream>>>(p[0], p[4], p[2], p[3], p[6], p[7], wih16);
        cvt_W  <<<64, 256, 0, stream>>>(p[8], W16);

        pre_mfma<<<dim3(M_TOT / 64, 21), 256, 0, stream>>>(A16, wih16, pre);
        lstm_scan<<<dim3(32, 2), 704, 0, stream>>>(pre, p[1], p[5], hcat16);
        lin_mfma<<<dim3(M_TOT / 64, 3), 256, 0, stream>>>(
            hcat16, W16, p[9], cur, outs[l], (l < 2) ? 1 : 0);
        cur = outs[l];
    }
}